// Round 1
// 8833.870 us; speedup vs baseline: 1.0638x; 1.0638x over previous
//
#include <hip/hip_runtime.h>
#include <math.h>

#define BATCH 64
#define SEQ   512
#define DIMK  1024
#define HID   1024
#define NWG   128
#define BLK   512
#define HPW   8           // hidden columns per WG
#define NCOL  32          // 4 gates * HPW
#define BPAD  1032        // LDS col stride (1024 + 8)
#define BH    (BATCH * HID)

typedef _Float16 h8  __attribute__((ext_vector_type(8)));
typedef float    f4  __attribute__((ext_vector_type(4)));
typedef float    fv4 __attribute__((ext_vector_type(4)));
typedef unsigned long long u64;

#define MFMA(a, b, c) __builtin_amdgcn_mfma_f32_16x16x32_f16(a, b, c, 0, 0, 0)

// 16-B fragment load, LLC-coherent (sc0 sc1), bypasses L1/L2 — no fences needed.
__device__ __forceinline__ h8 ldh8_llc(const _Float16* p){
    union { u64 q[2]; h8 v; } r;
    const u64* q = (const u64*)p;
    r.q[0] = __hip_atomic_load((u64*)(q + 0), __ATOMIC_RELAXED, __HIP_MEMORY_SCOPE_AGENT);
    r.q[1] = __hip_atomic_load((u64*)(q + 1), __ATOMIC_RELAXED, __HIP_MEMORY_SCOPE_AGENT);
    return r.v;
}

// Stage 32 columns (4 gates x 8 hidden) of four fp32 matrices into LDS as fp16 hi+lo planes.
__device__ __forceinline__ void stage32(const float* const M[4], int hb,
                                        _Float16* BlH, _Float16* BlL){
    int jj = threadIdx.x & 7;
    int kk = threadIdx.x >> 3;          // 0..63
    #pragma unroll
    for (int g = 0; g < 4; ++g){
        const float* Mg = M[g];
        #pragma unroll
        for (int it = 0; it < 16; ++it){
            int k = kk + 64 * it;
            float v = Mg[(long)k * HID + hb + jj];
            _Float16 hi = (_Float16)v;
            _Float16 lo = (_Float16)(v - (float)hi);
            BlH[(g * HPW + jj) * BPAD + k] = hi;
            BlL[(g * HPW + jj) * BPAD + k] = lo;
        }
    }
}

__global__ void __launch_bounds__(BLK, 2)
lstm_kernel(const float* x,
            const float* wf, const float* wi, const float* wo, const float* wc,
            const float* uf, const float* ui, const float* uo, const float* uc,
            const float* bfp, const float* bip, const float* bop, const float* bcp,
            float* out, unsigned* flags, _Float16* hbuf)
{
    __shared__ _Float16 BlH[NCOL * BPAD];          // U_hi (fp16), resident after phase 0
    __shared__ _Float16 BlL[NCOL * BPAD];          // U_lo residual
    __shared__ float    scr[2][64][NCOL + 4];      // k-split reduction / exchange
    __shared__ unsigned short hx[2][64][HPW];      // h pack staging (hi/lo planes)

    const int tid  = threadIdx.x;
    const int lane = tid & 63;
    const int wave = tid >> 6;
    const int mt   = wave & 3;          // m-tile (16 rows of batch)
    const int ks   = wave >> 2;         // k-half (512)
    const int hb   = blockIdx.x * HPW;

    const int arow = mt * 16 + (lane & 15);
    const int kb   = ks * 512 + ((lane >> 4) * 8);
    const int bcol = lane & 15;

    const float* Ws[4] = {wf, wi, wo, wc};
    const float* Us[4] = {uf, ui, uo, uc};

    // ---- Phase 0: gx = x0 @ W + b, fp16 split (x_hi/x_lo, W_hi/W_lo) ----
    stage32(Ws, hb, BlH, BlL);
    __syncthreads();

    f4 acc0 = {0.f,0.f,0.f,0.f}, acc1 = {0.f,0.f,0.f,0.f};
    {
        const float* Ar = x + (long)arow * (SEQ * DIMK);
        #pragma unroll 4
        for (int i = 0; i < 16; ++i){
            int k = kb + i * 32;
            fv4 xa = *(const fv4*)(Ar + k);
            fv4 xb = *(const fv4*)(Ar + k + 4);
            h8 xhi, xlo;
            #pragma unroll
            for (int j = 0; j < 4; ++j){
                xhi[j]   = (_Float16)xa[j];  xlo[j]   = (_Float16)(xa[j] - (float)xhi[j]);
                xhi[4+j] = (_Float16)xb[j];  xlo[4+j] = (_Float16)(xb[j] - (float)xhi[4+j]);
            }
            h8 b0h = *(const h8*)&BlH[ bcol       * BPAD + k];
            h8 b1h = *(const h8*)&BlH[(16 + bcol) * BPAD + k];
            h8 b0l = *(const h8*)&BlL[ bcol       * BPAD + k];
            h8 b1l = *(const h8*)&BlL[(16 + bcol) * BPAD + k];
            acc0 = MFMA(xhi, b0h, acc0); acc0 = MFMA(xlo, b0h, acc0); acc0 = MFMA(xhi, b0l, acc0);
            acc1 = MFMA(xhi, b1h, acc1); acc1 = MFMA(xlo, b1h, acc1); acc1 = MFMA(xhi, b1l, acc1);
        }
    }
    {
        int r0 = mt * 16 + ((lane >> 4) << 2);
        #pragma unroll
        for (int r = 0; r < 4; ++r){
            scr[ks][r0 + r][bcol]      = acc0[r];
            scr[ks][r0 + r][16 + bcol] = acc1[r];
        }
    }
    __syncthreads();

    const int eb = tid >> 3;            // batch row this thread owns
    const int ej = tid & 7;             // hidden col within WG slice
    float gx0 = scr[0][eb][ 0 + ej] + scr[1][eb][ 0 + ej] + bfp[hb + ej];
    float gx1 = scr[0][eb][ 8 + ej] + scr[1][eb][ 8 + ej] + bip[hb + ej];
    float gx2 = scr[0][eb][16 + ej] + scr[1][eb][16 + ej] + bop[hb + ej];
    float gx3 = scr[0][eb][24 + ej] + scr[1][eb][24 + ej] + bcp[hb + ej];
    stage32(Us, hb, BlH, BlL);          // U resident for the whole recurrence
    __syncthreads();

    // ---- Recurrence: 512 steps, LLC-coherent h exchange, no cache-maintenance ops ----
    float cstate = 0.f;
    const long obase = (long)eb * (SEQ * HID) + hb + ej;

    for (int t = 0; t < SEQ; ++t){
        const _Float16* hcH = hbuf + (t & 1) * (2 * BH);
        const _Float16* hcL = hcH + BH;
        _Float16* hnH = hbuf + ((t + 1) & 1) * (2 * BH);
        _Float16* hnL = hnH + BH;

        // A fragments: load once (hi & lo), reuse across U_hi and U_lo passes.
        h8 aH[16], aL[16];
        const _Float16* ApH = hcH + arow * HID + kb;
        const _Float16* ApL = hcL + arow * HID + kb;
        #pragma unroll
        for (int i = 0; i < 16; ++i) aH[i] = ldh8_llc(ApH + i * 32);
        #pragma unroll
        for (int i = 0; i < 16; ++i) aL[i] = ldh8_llc(ApL + i * 32);

        f4 z0 = {0.f,0.f,0.f,0.f}, z1 = {0.f,0.f,0.f,0.f};
        #pragma unroll
        for (int i = 0; i < 16; ++i){
            int k = kb + i * 32;
            h8 b0h = *(const h8*)&BlH[ bcol       * BPAD + k];
            h8 b1h = *(const h8*)&BlH[(16 + bcol) * BPAD + k];
            h8 b0l = *(const h8*)&BlL[ bcol       * BPAD + k];
            h8 b1l = *(const h8*)&BlL[(16 + bcol) * BPAD + k];
            z0 = MFMA(aH[i], b0h, z0); z0 = MFMA(aL[i], b0h, z0); z0 = MFMA(aH[i], b0l, z0);
            z1 = MFMA(aH[i], b1h, z1); z1 = MFMA(aL[i], b1h, z1); z1 = MFMA(aH[i], b1l, z1);
        }
        {
            int r0 = mt * 16 + ((lane >> 4) << 2);
            #pragma unroll
            for (int r = 0; r < 4; ++r){
                scr[ks][r0 + r][bcol]      = z0[r];
                scr[ks][r0 + r][16 + bcol] = z1[r];
            }
        }
        __syncthreads();

        float zf = gx0 + scr[0][eb][ 0 + ej] + scr[1][eb][ 0 + ej];
        float zi = gx1 + scr[0][eb][ 8 + ej] + scr[1][eb][ 8 + ej];
        float zo = gx2 + scr[0][eb][16 + ej] + scr[1][eb][16 + ej];
        float zc = gx3 + scr[0][eb][24 + ej] + scr[1][eb][24 + ej];
        float f  = 1.0f / (1.0f + expf(-zf));
        float ii = 1.0f / (1.0f + expf(-zi));
        float o  = 1.0f / (1.0f + expf(-zo));
        float ch = tanhf(zc);
        cstate   = f * cstate + ii * ch;
        float hv = o * tanhf(cstate);
        out[obase + (long)t * HID] = hv;

        _Float16 hhi = (_Float16)hv;
        _Float16 hlo = (_Float16)(hv - (float)hhi);
        hx[0][eb][ej] = __builtin_bit_cast(unsigned short, hhi);
        hx[1][eb][ej] = __builtin_bit_cast(unsigned short, hlo);
        __syncthreads();                 // hx complete; also protects scr for next step

        // Packed LLC-coherent h store: 512 threads cover 2 planes x 64 b x 4 dwords.
        {
            int p = tid >> 8, rr = tid & 255, b = rr >> 2, w = rr & 3;
            unsigned v = (unsigned)hx[p][b][2*w] | ((unsigned)hx[p][b][2*w + 1] << 16);
            unsigned* dst = (unsigned*)(p ? hnL : hnH) + b * (HID / 2) + (hb >> 1) + w;
            __hip_atomic_store(dst, v, __ATOMIC_RELAXED, __HIP_MEMORY_SCOPE_AGENT);
        }

        if (t < SEQ - 1){
            __syncthreads();             // drains every wave's vmcnt: h stores acked at LLC
            // Decentralized epoch barrier: per-WG flag on its own 128-B line.
            // Arrive: one relaxed agent store (parallel across WGs, no RMW serialization).
            if (tid == 0)
                __hip_atomic_store(flags + ((unsigned)blockIdx.x << 5), (unsigned)(t + 1),
                                   __ATOMIC_RELAXED, __HIP_MEMORY_SCOPE_AGENT);
            // Wait: threads 0..127 each poll one distinct flag line (monotone epochs).
            if (tid < NWG){
                const unsigned* f = flags + (tid << 5);
                while (__hip_atomic_load(f, __ATOMIC_RELAXED, __HIP_MEMORY_SCOPE_AGENT)
                       < (unsigned)(t + 1))
                    __builtin_amdgcn_s_sleep(1);
            }
            __syncthreads();
        }
    }
}

extern "C" void kernel_launch(void* const* d_in, const int* in_sizes, int n_in,
                              void* d_out, int out_size, void* d_ws, size_t ws_size,
                              hipStream_t stream)
{
    const float* x  = (const float*)d_in[0];
    const float* wf = (const float*)d_in[1];
    const float* wi = (const float*)d_in[2];
    const float* wo = (const float*)d_in[3];
    const float* wc = (const float*)d_in[4];
    const float* uf = (const float*)d_in[5];
    const float* ui = (const float*)d_in[6];
    const float* uo = (const float*)d_in[7];
    const float* uc = (const float*)d_in[8];
    const float* bf = (const float*)d_in[9];
    const float* bi = (const float*)d_in[10];
    const float* bo = (const float*)d_in[11];
    const float* bc = (const float*)d_in[12];
    float* out = (float*)d_out;

    unsigned*  flags = (unsigned*)d_ws;                       // NWG x 128B flag lines
    _Float16*  hbuf  = (_Float16*)((char*)d_ws + 16384);      // h ping-pong (hi+lo planes)

    // zero flag lines + both h ping-pong buffers; h0 = 0
    hipMemsetAsync(d_ws, 0, 16384 + (size_t)2 * 2 * BH * sizeof(_Float16), stream);

    void* args[] = { &x, &wf, &wi, &wo, &wc, &uf, &ui, &uo, &uc,
                     &bf, &bi, &bo, &bc, &out, &flags, &hbuf };
    hipLaunchCooperativeKernel((void*)lstm_kernel, dim3(NWG), dim3(BLK), args, 0, stream);
}

// Round 2
// 5155.919 us; speedup vs baseline: 1.8227x; 1.7133x over previous
//
#include <hip/hip_runtime.h>
#include <math.h>

#define BATCH 64
#define SEQ   512
#define DIMK  1024
#define HID   1024
#define NWG   256         // 128 col-groups x 2 batch-halves
#define BLK   512
#define HPW   8           // hidden columns per WG
#define NCOL  32          // 4 gates * HPW
#define BPAD  1032        // LDS col stride (1024 + 8)
#define BH    (BATCH * HID)
#define ROWS  32          // batch rows per WG

typedef _Float16 h8  __attribute__((ext_vector_type(8)));
typedef float    f4  __attribute__((ext_vector_type(4)));
typedef float    fv4 __attribute__((ext_vector_type(4)));
typedef unsigned long long u64;

#define MFMA(a, b, c) __builtin_amdgcn_mfma_f32_16x16x32_f16(a, b, c, 0, 0, 0)

// 16-B fragment load, LLC-coherent, bypasses L1/L2 — no fences needed.
__device__ __forceinline__ h8 ldh8_llc(const _Float16* p){
    union { u64 q[2]; h8 v; } r;
    const u64* q = (const u64*)p;
    r.q[0] = __hip_atomic_load((u64*)(q + 0), __ATOMIC_RELAXED, __HIP_MEMORY_SCOPE_AGENT);
    r.q[1] = __hip_atomic_load((u64*)(q + 1), __ATOMIC_RELAXED, __HIP_MEMORY_SCOPE_AGENT);
    return r.v;
}

// Stage 32 columns (4 gates x 8 hidden) of four fp32 matrices into LDS as fp16 hi+lo planes.
__device__ __forceinline__ void stage32(const float* const M[4], int hb,
                                        _Float16* BlH, _Float16* BlL){
    int jj = threadIdx.x & 7;
    int kk = threadIdx.x >> 3;          // 0..63
    #pragma unroll
    for (int g = 0; g < 4; ++g){
        const float* Mg = M[g];
        #pragma unroll
        for (int it = 0; it < 16; ++it){
            int k = kk + 64 * it;
            float v = Mg[(long)k * HID + hb + jj];
            _Float16 hi = (_Float16)v;
            _Float16 lo = (_Float16)(v - (float)hi);
            BlH[(g * HPW + jj) * BPAD + k] = hi;
            BlL[(g * HPW + jj) * BPAD + k] = lo;
        }
    }
}

__global__ void __launch_bounds__(BLK, 2)
lstm_kernel(const float* x,
            const float* wf, const float* wi, const float* wo, const float* wc,
            const float* uf, const float* ui, const float* uo, const float* uc,
            const float* bfp, const float* bip, const float* bop, const float* bcp,
            float* out, unsigned* flags, _Float16* hbuf)
{
    __shared__ _Float16 BlH[NCOL * BPAD];          // U_hi staging (dead after B-reg load)
    __shared__ _Float16 BlL[NCOL * BPAD];          // U_lo staging
    __shared__ float    scr[4][ROWS][NCOL + 4];    // 4-way k-split reduction

    const int tid  = threadIdx.x;
    const int lane = tid & 63;
    const int wave = tid >> 6;
    const int mt   = wave & 1;          // m-tile (16 rows of the 32-row slice)
    const int ks   = wave >> 1;         // k-quarter (256)
    const int cg   = blockIdx.x >> 1;   // col-group
    const int bh   = blockIdx.x & 1;    // batch half
    const int hb   = cg * HPW;

    const int arow = mt * 16 + (lane & 15);      // local row 0..31
    const int grow = bh * ROWS + arow;           // global batch row
    const int kb   = ks * 256 + ((lane >> 4) * 8);
    const int bcol = lane & 15;

    const float* Ws[4] = {wf, wi, wo, wc};
    const float* Us[4] = {uf, ui, uo, uc};

    // ---- Phase 0: gx = x0 @ W + b ----
    stage32(Ws, hb, BlH, BlL);
    __syncthreads();

    f4 acc0 = {0.f,0.f,0.f,0.f}, acc1 = {0.f,0.f,0.f,0.f};
    {
        const float* Ar = x + (long)grow * (SEQ * DIMK);
        #pragma unroll
        for (int i = 0; i < 8; ++i){
            int k = kb + i * 32;
            fv4 xa = *(const fv4*)(Ar + k);
            fv4 xb = *(const fv4*)(Ar + k + 4);
            h8 xhi, xlo;
            #pragma unroll
            for (int j = 0; j < 4; ++j){
                xhi[j]   = (_Float16)xa[j];  xlo[j]   = (_Float16)(xa[j] - (float)xhi[j]);
                xhi[4+j] = (_Float16)xb[j];  xlo[4+j] = (_Float16)(xb[j] - (float)xhi[4+j]);
            }
            h8 b0h = *(const h8*)&BlH[ bcol       * BPAD + k];
            h8 b1h = *(const h8*)&BlH[(16 + bcol) * BPAD + k];
            h8 b0l = *(const h8*)&BlL[ bcol       * BPAD + k];
            h8 b1l = *(const h8*)&BlL[(16 + bcol) * BPAD + k];
            acc0 = MFMA(xhi, b0h, acc0); acc0 = MFMA(xlo, b0h, acc0); acc0 = MFMA(xhi, b0l, acc0);
            acc1 = MFMA(xhi, b1h, acc1); acc1 = MFMA(xlo, b1h, acc1); acc1 = MFMA(xhi, b1l, acc1);
        }
    }
    {
        int r0 = mt * 16 + ((lane >> 4) << 2);
        #pragma unroll
        for (int r = 0; r < 4; ++r){
            scr[ks][r0 + r][bcol]      = acc0[r];
            scr[ks][r0 + r][16 + bcol] = acc1[r];
        }
    }
    __syncthreads();

    const int eb = tid >> 3;            // local batch row (valid tid<256)
    const int ej = tid & 7;             // hidden col within WG slice
    float gx0 = 0.f, gx1 = 0.f, gx2 = 0.f, gx3 = 0.f;
    if (tid < 256){
        gx0 = scr[0][eb][ 0+ej] + scr[1][eb][ 0+ej] + scr[2][eb][ 0+ej] + scr[3][eb][ 0+ej] + bfp[hb + ej];
        gx1 = scr[0][eb][ 8+ej] + scr[1][eb][ 8+ej] + scr[2][eb][ 8+ej] + scr[3][eb][ 8+ej] + bip[hb + ej];
        gx2 = scr[0][eb][16+ej] + scr[1][eb][16+ej] + scr[2][eb][16+ej] + scr[3][eb][16+ej] + bop[hb + ej];
        gx3 = scr[0][eb][24+ej] + scr[1][eb][24+ej] + scr[2][eb][24+ej] + scr[3][eb][24+ej] + bcp[hb + ej];
    }
    stage32(Us, hb, BlH, BlL);          // stage U once
    __syncthreads();

    // ---- U fragments into registers: invariant across all 512 steps ----
    h8 Bh0[8], Bh1[8], Bl0[8], Bl1[8];
    #pragma unroll
    for (int i = 0; i < 8; ++i){
        int k = kb + i * 32;
        Bh0[i] = *(const h8*)&BlH[ bcol       * BPAD + k];
        Bh1[i] = *(const h8*)&BlH[(16 + bcol) * BPAD + k];
        Bl0[i] = *(const h8*)&BlL[ bcol       * BPAD + k];
        Bl1[i] = *(const h8*)&BlL[(16 + bcol) * BPAD + k];
    }

    // ---- Recurrence: 512 steps ----
    float cstate = 0.f;
    const int  orow  = bh * ROWS + eb;                 // global row (valid tid<256)
    const long obase = (long)orow * (SEQ * HID) + hb + ej;

    for (int t = 0; t < SEQ; ++t){
        const _Float16* hcH = hbuf + (t & 1) * (2 * BH);
        const _Float16* hcL = hcH + BH;
        _Float16* hnH = hbuf + ((t + 1) & 1) * (2 * BH);
        _Float16* hnL = hnH + BH;

        h8 aH[8], aL[8];
        const _Float16* ApH = hcH + grow * HID + kb;
        const _Float16* ApL = hcL + grow * HID + kb;
        #pragma unroll
        for (int i = 0; i < 8; ++i) aH[i] = ldh8_llc(ApH + i * 32);
        #pragma unroll
        for (int i = 0; i < 8; ++i) aL[i] = ldh8_llc(ApL + i * 32);

        f4 z0 = {0.f,0.f,0.f,0.f}, z1 = {0.f,0.f,0.f,0.f};
        #pragma unroll
        for (int i = 0; i < 8; ++i){
            z0 = MFMA(aH[i], Bh0[i], z0); z0 = MFMA(aL[i], Bh0[i], z0); z0 = MFMA(aH[i], Bl0[i], z0);
            z1 = MFMA(aH[i], Bh1[i], z1); z1 = MFMA(aL[i], Bh1[i], z1); z1 = MFMA(aH[i], Bl1[i], z1);
        }
        {
            int r0 = mt * 16 + ((lane >> 4) << 2);
            #pragma unroll
            for (int r = 0; r < 4; ++r){
                scr[ks][r0 + r][bcol]      = z0[r];
                scr[ks][r0 + r][16 + bcol] = z1[r];
            }
        }
        __syncthreads();

        if (tid < 256){
            float zf = gx0 + scr[0][eb][ 0+ej] + scr[1][eb][ 0+ej] + scr[2][eb][ 0+ej] + scr[3][eb][ 0+ej];
            float zi = gx1 + scr[0][eb][ 8+ej] + scr[1][eb][ 8+ej] + scr[2][eb][ 8+ej] + scr[3][eb][ 8+ej];
            float zo = gx2 + scr[0][eb][16+ej] + scr[1][eb][16+ej] + scr[2][eb][16+ej] + scr[3][eb][16+ej];
            float zc = gx3 + scr[0][eb][24+ej] + scr[1][eb][24+ej] + scr[2][eb][24+ej] + scr[3][eb][24+ej];
            float f  = 1.0f / (1.0f + expf(-zf));
            float ii = 1.0f / (1.0f + expf(-zi));
            float o  = 1.0f / (1.0f + expf(-zo));
            float ch = tanhf(zc);
            cstate   = f * cstate + ii * ch;
            float hv = o * tanhf(cstate);
            out[obase + (long)t * HID] = hv;

            _Float16 hhi = (_Float16)hv;
            _Float16 hlo = (_Float16)(hv - (float)hhi);
            int hoff = orow * HID + hb + ej;
            __hip_atomic_store((unsigned short*)hnH + hoff,
                               __builtin_bit_cast(unsigned short, hhi),
                               __ATOMIC_RELAXED, __HIP_MEMORY_SCOPE_AGENT);
            __hip_atomic_store((unsigned short*)hnL + hoff,
                               __builtin_bit_cast(unsigned short, hlo),
                               __ATOMIC_RELAXED, __HIP_MEMORY_SCOPE_AGENT);
        }
        __syncthreads();                 // drains every wave's vmcnt: h/out stores acked

        if (t < SEQ - 1){
            // Decentralized epoch barrier: per-WG flag on its own 128-B line.
            if (tid == 0)
                __hip_atomic_store(flags + ((unsigned)blockIdx.x << 5), (unsigned)(t + 1),
                                   __ATOMIC_RELAXED, __HIP_MEMORY_SCOPE_AGENT);
            if (tid < NWG){
                const unsigned* fp = flags + (tid << 5);
                while (__hip_atomic_load(fp, __ATOMIC_RELAXED, __HIP_MEMORY_SCOPE_AGENT)
                       < (unsigned)(t + 1))
                    __builtin_amdgcn_s_sleep(1);
            }
            __syncthreads();
        }
    }
}

extern "C" void kernel_launch(void* const* d_in, const int* in_sizes, int n_in,
                              void* d_out, int out_size, void* d_ws, size_t ws_size,
                              hipStream_t stream)
{
    const float* x  = (const float*)d_in[0];
    const float* wf = (const float*)d_in[1];
    const float* wi = (const float*)d_in[2];
    const float* wo = (const float*)d_in[3];
    const float* wc = (const float*)d_in[4];
    const float* uf = (const float*)d_in[5];
    const float* ui = (const float*)d_in[6];
    const float* uo = (const float*)d_in[7];
    const float* uc = (const float*)d_in[8];
    const float* bf = (const float*)d_in[9];
    const float* bi = (const float*)d_in[10];
    const float* bo = (const float*)d_in[11];
    const float* bc = (const float*)d_in[12];
    float* out = (float*)d_out;

    unsigned*  flags = (unsigned*)d_ws;                       // NWG x 128B flag lines
    _Float16*  hbuf  = (_Float16*)((char*)d_ws + 32768);      // h ping-pong (hi+lo planes)

    // zero flag lines + both h ping-pong buffers; h0 = 0
    hipMemsetAsync(d_ws, 0, 32768 + (size_t)2 * 2 * BH * sizeof(_Float16), stream);

    void* args[] = { &x, &wf, &wi, &wo, &wc, &uf, &ui, &uo, &uc,
                     &bf, &bi, &bo, &bc, &out, &flags, &hbuf };
    hipLaunchCooperativeKernel((void*)lstm_kernel, dim3(NWG), dim3(BLK), args, 0, stream);
}